// Round 14
// baseline (592.335 us; speedup 1.0000x reference)
//
#include <hip/hip_runtime.h>
#include <hip/hip_bf16.h>
#include <math.h>

#define LQ 5440
#define CDIM 256
#define BATCH 2
#define FFDIM 1024

typedef __attribute__((ext_vector_type(8))) short bf16x8;
typedef __attribute__((ext_vector_type(4))) float f32x4;

typedef __attribute__((address_space(1))) void* gas1_t;
typedef __attribute__((address_space(3))) void* las3_t;

__device__ __forceinline__ void async16(const void* g, void* l) {
  __builtin_amdgcn_global_load_lds((gas1_t)g, (las3_t)l, 16, 0, 0);
}

#define WAIT_VM5() asm volatile("s_waitcnt vmcnt(5)" ::: "memory")
#define WAIT_VM4() asm volatile("s_waitcnt vmcnt(4)" ::: "memory")
#define WAIT_VM3() asm volatile("s_waitcnt vmcnt(3)" ::: "memory")
#define WAIT_VM2() asm volatile("s_waitcnt vmcnt(2)" ::: "memory")
#define WAIT_VM0() asm volatile("s_waitcnt vmcnt(0)" ::: "memory")

__device__ __forceinline__ float b2f(unsigned short u) {
  return __uint_as_float((unsigned)u << 16);
}

// chunk (0..84) -> level, row0 (64-row chunks across the 4 levels)
__device__ __forceinline__ void get_chunk(int chunk, int& l, int& row0) {
  if (chunk < 64)      { l = 0; row0 = chunk * 64; }
  else if (chunk < 80) { l = 1; row0 = (chunk - 64) * 64; }
  else if (chunk < 84) { l = 2; row0 = (chunk - 80) * 64; }
  else                 { l = 3; row0 = 0; }
}

// ---------------------------------------------------------------------------
// Input proj: all 4 levels in ONE launch. 128x128 tiles, REMAP epilogue writes
// token-major fp32 x (pre-GN; fp32 needed for GN accuracy). grid = 170.
// ---------------------------------------------------------------------------
__global__ __launch_bounds__(256, 2) void input_proj_kernel(
    const __hip_bfloat16* __restrict__ ftb, const __hip_bfloat16* __restrict__ proj_wb,
    const float* __restrict__ proj_b, float* __restrict__ x) {
  const int HWs[4] = {4096, 1024, 256, 64};
  const int STs[4] = {0, 4096, 5120, 5376};
  int i = blockIdx.x, l, j;
  if (i < 128)      { l = 0; j = i; }
  else if (i < 160) { l = 1; j = i - 128; }
  else if (i < 168) { l = 2; j = i - 160; }
  else              { l = 3; j = i - 168; }
  const int bm = (j >> 1) * 128, bn = (j & 1) * 128;
  const int mrows = HWs[l];
  const long obase = (long)STs[l] * 256;
  const long obstride = (long)LQ * 256;
  const __hip_bfloat16* A = ftb + (size_t)2 * STs[l] * 256;
  const __hip_bfloat16* Wt = proj_wb + (size_t)l * 65536;
  const float* bias = proj_b + l * 256;
  const int K = 256, N = 256;

  __shared__ __hip_bfloat16 As[3][128 * 32];
  __shared__ __hip_bfloat16 Bs[3][128 * 32];
  const int tid = threadIdx.x;
  const int lane = tid & 63, wave = tid >> 6;
  const int wr = wave >> 1, wc = wave & 1;
  const int srow = tid >> 2;
  const int scol = (tid & 3) * 8;
  const int lo0 = srow * 32 + scol;
  const int lo1 = (64 + srow) * 32 + scol;
  const __hip_bfloat16* ga0 = A + (size_t)(bm + srow) * K + scol;
  const __hip_bfloat16* ga1 = A + (size_t)(bm + 64 + srow) * K + scol;
  const __hip_bfloat16* gb0 = Wt + (size_t)(bn + srow) * K + scol;
  const __hip_bfloat16* gb1 = Wt + (size_t)(bn + 64 + srow) * K + scol;

  const int nt = K >> 5;
  async16(ga0, &As[0][lo0]);
  async16(ga1, &As[0][lo1]);
  async16(gb0, &Bs[0][lo0]);
  async16(gb1, &Bs[0][lo1]);
  async16(ga0 + 32, &As[1][lo0]);
  async16(ga1 + 32, &As[1][lo1]);
  async16(gb0 + 32, &Bs[1][lo0]);
  async16(gb1 + 32, &Bs[1][lo1]);

  f32x4 acc[4][4] = {};
  const int fr = lane & 15;
  const int ksub = (lane >> 4) * 8;
  int cur = 0, nxt = 2;
  for (int t = 0; t < nt; ++t) {
    if (t == nt - 1) WAIT_VM0(); else WAIT_VM4();
    __builtin_amdgcn_s_barrier();
    asm volatile("" ::: "memory");
    bf16x8 af[4], bfv[4];
#pragma unroll
    for (int mi = 0; mi < 4; ++mi)
      af[mi] = *(const bf16x8*)&As[cur][(wr * 64 + mi * 16 + fr) * 32 + ksub];
#pragma unroll
    for (int nj = 0; nj < 4; ++nj)
      bfv[nj] = *(const bf16x8*)&Bs[cur][(wc * 64 + nj * 16 + fr) * 32 + ksub];
    if (t + 2 < nt) {
      const int ko = (t + 2) * 32;
      async16(ga0 + ko, &As[nxt][lo0]);
      async16(ga1 + ko, &As[nxt][lo1]);
      async16(gb0 + ko, &Bs[nxt][lo0]);
      async16(gb1 + ko, &Bs[nxt][lo1]);
    }
#pragma unroll
    for (int mi = 0; mi < 4; ++mi)
#pragma unroll
      for (int nj = 0; nj < 4; ++nj)
        acc[mi][nj] = __builtin_amdgcn_mfma_f32_16x16x32_bf16(af[mi], bfv[nj],
                                                              acc[mi][nj], 0, 0, 0);
    cur = (cur == 2) ? 0 : cur + 1;
    nxt = (nxt == 2) ? 0 : nxt + 1;
  }

  const int cc = lane & 15;
  const int rbase = (lane >> 4) * 4;
  float bcol[4];
#pragma unroll
  for (int nj = 0; nj < 4; ++nj) bcol[nj] = bias[bn + wc * 64 + nj * 16 + cc];
#pragma unroll
  for (int mi = 0; mi < 4; ++mi)
#pragma unroll
    for (int nj = 0; nj < 4; ++nj) {
      int col = bn + wc * 64 + nj * 16 + cc;
#pragma unroll
      for (int r = 0; r < 4; ++r) {
        int row = bm + wr * 64 + mi * 16 + rbase + r;
        size_t oaddr = (size_t)obase +
                       (row < mrows ? (size_t)row * N
                                    : (size_t)obstride + (size_t)(row - mrows) * N) +
                       col;
        x[oaddr] = acc[mi][nj][r] + bcol[nj];
      }
    }
}

// ---------------------------------------------------------------------------
// 64x128-tile GEMM body (4 waves, each 64 rows x 32 cols).
// ---------------------------------------------------------------------------
template <bool RELU, bool OUT_F32, bool OUT_B16>
__device__ __forceinline__ void gemm64_body(
    const __hip_bfloat16* __restrict__ A, const __hip_bfloat16* __restrict__ Wt,
    const float* __restrict__ bias, float* __restrict__ C,
    __hip_bfloat16* __restrict__ Cb, int bm, int bn, int N, int K,
    __hip_bfloat16 (*As)[64 * 32], __hip_bfloat16 (*Bs)[128 * 32]) {
  const int tid = threadIdx.x;
  const int lane = tid & 63, wv = tid >> 6;
  const int srow = tid >> 2, scol = (tid & 3) * 8;
  const int loA = srow * 32 + scol;
  const int loB1 = (64 + srow) * 32 + scol;
  const __hip_bfloat16* ga = A + (size_t)(bm + srow) * K + scol;
  const __hip_bfloat16* gb0 = Wt + (size_t)(bn + srow) * K + scol;
  const __hip_bfloat16* gb1 = Wt + (size_t)(bn + 64 + srow) * K + scol;
  const int nt = K >> 5;
  async16(ga, &As[0][loA]);
  async16(gb0, &Bs[0][loA]);
  async16(gb1, &Bs[0][loB1]);
  async16(ga + 32, &As[1][loA]);
  async16(gb0 + 32, &Bs[1][loA]);
  async16(gb1 + 32, &Bs[1][loB1]);

  f32x4 acc[4][2] = {};
  const int fr = lane & 15, ksub = (lane >> 4) * 8;
  int cur = 0, nxt = 2;
  for (int t = 0; t < nt; ++t) {
    if (t == nt - 1) WAIT_VM0(); else WAIT_VM3();
    __builtin_amdgcn_s_barrier();
    asm volatile("" ::: "memory");
    bf16x8 af[4], bfv[2];
#pragma unroll
    for (int mi = 0; mi < 4; ++mi)
      af[mi] = *(const bf16x8*)&As[cur][(mi * 16 + fr) * 32 + ksub];
#pragma unroll
    for (int nj = 0; nj < 2; ++nj)
      bfv[nj] = *(const bf16x8*)&Bs[cur][(wv * 32 + nj * 16 + fr) * 32 + ksub];
    if (t + 2 < nt) {
      const int ko = (t + 2) * 32;
      async16(ga + ko, &As[nxt][loA]);
      async16(gb0 + ko, &Bs[nxt][loA]);
      async16(gb1 + ko, &Bs[nxt][loB1]);
    }
#pragma unroll
    for (int mi = 0; mi < 4; ++mi)
#pragma unroll
      for (int nj = 0; nj < 2; ++nj)
        acc[mi][nj] = __builtin_amdgcn_mfma_f32_16x16x32_bf16(af[mi], bfv[nj],
                                                              acc[mi][nj], 0, 0, 0);
    cur = (cur == 2) ? 0 : cur + 1;
    nxt = (nxt == 2) ? 0 : nxt + 1;
  }
  const int cc = lane & 15;
  const int rbase = (lane >> 4) * 4;
#pragma unroll
  for (int nj = 0; nj < 2; ++nj) {
    int col = bn + wv * 32 + nj * 16 + cc;
    float bb = bias[col];
#pragma unroll
    for (int mi = 0; mi < 4; ++mi)
#pragma unroll
      for (int r = 0; r < 4; ++r) {
        int row = bm + mi * 16 + rbase + r;
        float v = acc[mi][nj][r] + bb;
        if (RELU) v = fmaxf(v, 0.f);
        if (OUT_F32) C[(size_t)row * N + col] = v;
        if (OUT_B16) Cb[(size_t)row * N + col] = __float2bfloat16(v);
      }
  }
}

// Dual GEMM: blocks [0,340) -> value proj; [340,850) -> sampling proj (N=384)
__global__ __launch_bounds__(256, 4) void gemm_dual_kernel(
    const __hip_bfloat16* __restrict__ xb, const __hip_bfloat16* __restrict__ vw,
    const float* __restrict__ vb, __hip_bfloat16* __restrict__ valb,
    const __hip_bfloat16* __restrict__ qb, const __hip_bfloat16* __restrict__ sowa,
    const float* __restrict__ sbias, float* __restrict__ comb) {
  __shared__ __hip_bfloat16 As[3][64 * 32];
  __shared__ __hip_bfloat16 Bs[3][128 * 32];
  if (blockIdx.x < 340) {
    int i = blockIdx.x;
    gemm64_body<false, false, true>(xb, vw, vb, nullptr, valb, (i >> 1) * 64,
                                    (i & 1) * 128, 256, 256, As, Bs);
  } else {
    int j = blockIdx.x - 340;
    gemm64_body<false, true, false>(qb, sowa, sbias, comb, nullptr, (j / 3) * 64,
                                    (j % 3) * 128, 384, 256, As, Bs);
  }
}

// ffn1: relu(xb @ w1^T + b1) -> ff1b bf16. grid = 1360 blocks.
__global__ __launch_bounds__(256, 4) void ffn1_kernel(
    const __hip_bfloat16* __restrict__ xb, const __hip_bfloat16* __restrict__ w1,
    const float* __restrict__ b1, __hip_bfloat16* __restrict__ ff1b) {
  __shared__ __hip_bfloat16 As[3][64 * 32];
  __shared__ __hip_bfloat16 Bs[3][128 * 32];
  int i = blockIdx.x;
  gemm64_body<true, false, true>(xb, w1, b1, nullptr, ff1b, (i >> 3) * 64,
                                 (i & 7) * 128, 1024, 256, As, Bs);
}

// ---------------------------------------------------------------------------
// Fused GEMM (N=256) + residual(bf16 xb) + LayerNorm, 32-row tiles (grid 340).
// ---------------------------------------------------------------------------
template <bool EMIT_Q>
__global__ __launch_bounds__(256, 2) void gemm_ln_kernel(
    const __hip_bfloat16* __restrict__ A, const __hip_bfloat16* __restrict__ Wt,
    const float* __restrict__ bias, __hip_bfloat16* xb,
    __hip_bfloat16* __restrict__ qb, const float* __restrict__ pos,
    const float* __restrict__ lnw, const float* __restrict__ lnb, int K) {
  __shared__ __hip_bfloat16 As[3][32 * 32];
  __shared__ __hip_bfloat16 Bs[3][256 * 32];
  __shared__ float sred[4][32], ssred[4][32];
  const int tid = threadIdx.x;
  const int bm = blockIdx.x * 32;
  const int lane = tid & 63, wv = tid >> 6;
  const int srow = tid >> 2;
  const int arow = srow & 31;
  const int scol = (tid & 3) * 8;
  const int loA = arow * 32 + scol;
  const __hip_bfloat16* ga = A + (size_t)(bm + arow) * K + scol;
  const __hip_bfloat16* gb = Wt + (size_t)srow * K + scol;

  const int nt = K >> 5;
  auto stage = [&](int t, int buf) {
    const int ko = t * 32;
    async16(ga + ko, &As[buf][loA]);
#pragma unroll
    for (int i = 0; i < 4; ++i)
      async16(gb + (size_t)(64 * i) * K + ko, &Bs[buf][(64 * i + srow) * 32 + scol]);
  };
  stage(0, 0);
  stage(1, 1);

  f32x4 acc[2][4] = {};
  const int fr = lane & 15;
  const int ksub = (lane >> 4) * 8;

  int cur = 0, nxt = 2;
  for (int t = 0; t < nt; ++t) {
    if (t == nt - 1) WAIT_VM0(); else WAIT_VM5();
    __builtin_amdgcn_s_barrier();
    asm volatile("" ::: "memory");
    bf16x8 af[2], bfv[4];
#pragma unroll
    for (int mi = 0; mi < 2; ++mi)
      af[mi] = *(const bf16x8*)&As[cur][(mi * 16 + fr) * 32 + ksub];
#pragma unroll
    for (int nj = 0; nj < 4; ++nj)
      bfv[nj] = *(const bf16x8*)&Bs[cur][(wv * 64 + nj * 16 + fr) * 32 + ksub];
    if (t + 2 < nt) stage(t + 2, nxt);
#pragma unroll
    for (int mi = 0; mi < 2; ++mi)
#pragma unroll
      for (int nj = 0; nj < 4; ++nj)
        acc[mi][nj] = __builtin_amdgcn_mfma_f32_16x16x32_bf16(af[mi], bfv[nj],
                                                              acc[mi][nj], 0, 0, 0);
    cur = (cur == 2) ? 0 : cur + 1;
    nxt = (nxt == 2) ? 0 : nxt + 1;
  }

  const int cc = lane & 15;
  const int rbase = (lane >> 4) * 4;
  float bcol[4], wcol[4], bncol[4];
#pragma unroll
  for (int nj = 0; nj < 4; ++nj) {
    int col = wv * 64 + nj * 16 + cc;
    bcol[nj] = bias[col];
    wcol[nj] = lnw[col];
    bncol[nj] = lnb[col];
  }
#pragma unroll
  for (int mi = 0; mi < 2; ++mi)
#pragma unroll
    for (int r = 0; r < 4; ++r) {
      int grow = bm + mi * 16 + rbase + r;
#pragma unroll
      for (int nj = 0; nj < 4; ++nj) {
        int col = wv * 64 + nj * 16 + cc;
        acc[mi][nj][r] += bcol[nj] + __bfloat162float(xb[(size_t)grow * 256 + col]);
      }
    }
#pragma unroll
  for (int mi = 0; mi < 2; ++mi)
#pragma unroll
    for (int r = 0; r < 4; ++r) {
      float s = 0.f, ssq = 0.f;
#pragma unroll
      for (int nj = 0; nj < 4; ++nj) {
        float v = acc[mi][nj][r];
        s += v;
        ssq += v * v;
      }
#pragma unroll
      for (int m = 1; m < 16; m <<= 1) {
        s += __shfl_xor(s, m);
        ssq += __shfl_xor(ssq, m);
      }
      if (cc == 0) {
        int row = mi * 16 + rbase + r;
        sred[wv][row] = s;
        ssred[wv][row] = ssq;
      }
    }
  __syncthreads();
#pragma unroll
  for (int mi = 0; mi < 2; ++mi)
#pragma unroll
    for (int r = 0; r < 4; ++r) {
      int row = mi * 16 + rbase + r;
      int grow = bm + row;
      float s = sred[0][row] + sred[1][row] + sred[2][row] + sred[3][row];
      float ssq = ssred[0][row] + ssred[1][row] + ssred[2][row] + ssred[3][row];
      float mu = s * (1.0f / 256.0f);
      float var = ssq * (1.0f / 256.0f) - mu * mu;
      float rsig = rsqrtf(var + 1e-5f);
      int tokp = grow >= LQ ? grow - LQ : grow;
#pragma unroll
      for (int nj = 0; nj < 4; ++nj) {
        int col = wv * 64 + nj * 16 + cc;
        float xn = (acc[mi][nj][r] - mu) * rsig * wcol[nj] + bncol[nj];
        xb[(size_t)grow * 256 + col] = __float2bfloat16(xn);
        if (EMIT_Q)
          qb[(size_t)grow * 256 + col] =
              __float2bfloat16(xn + pos[(size_t)tokp * 256 + col]);
      }
    }
}

// ---------------------------------------------------------------------------
// conv1 implicit GEMM (NHWC), 64-pixel tiles, 72-step pipelined K-loop.
// ---------------------------------------------------------------------------
__global__ __launch_bounds__(256, 4) void conv1_mfma_kernel(
    const __hip_bfloat16* __restrict__ xb, const __hip_bfloat16* __restrict__ wc1,
    const float* __restrict__ bias, const __hip_bfloat16* __restrict__ zerob,
    __hip_bfloat16* __restrict__ c1o) {
  __shared__ __hip_bfloat16 As[3][64 * 32];
  __shared__ __hip_bfloat16 Bs[3][64 * 32];
  const int tid = threadIdx.x;
  const int b = blockIdx.x >> 6;
  const int pm = (blockIdx.x & 63) * 64;
  const int lane = tid & 63, wave = tid >> 6;
  const int sr = tid >> 2;
  const int sc = (tid & 3) * 8;
  const int lo = sr * 32 + sc;
  f32x4 acc[4] = {};
  const int fr = lane & 15, ksub = (lane >> 4) * 8;

  auto stage = [&](int kt, int buf) {
    int tap = kt >> 3;
    int kk = (kt & 7) * 32;
    int dy = tap / 3 - 1, dx = tap % 3 - 1;
    int hw = pm + sr;
    int y = (hw >> 6) + dy, x = (hw & 63) + dx;
    bool ok = (y >= 0 && y < 64 && x >= 0 && x < 64);
    const __hip_bfloat16* s =
        xb + ((size_t)(b * LQ) + y * 64 + x) * 256 + kk + sc;
    const __hip_bfloat16* wsrc = wc1 + (size_t)sr * 2304 + tap * 256 + kk + sc;
    async16(ok ? s : zerob, &As[buf][lo]);
    async16(wsrc, &Bs[buf][lo]);
  };
  stage(0, 0);
  stage(1, 1);
  int cur = 0, nxt = 2;
  for (int kt = 0; kt < 72; ++kt) {
    if (kt == 71) WAIT_VM0(); else WAIT_VM2();
    __builtin_amdgcn_s_barrier();
    asm volatile("" ::: "memory");
    bf16x8 af;
    bf16x8 bfv[4];
    af = *(const bf16x8*)&As[cur][(wave * 16 + fr) * 32 + ksub];
#pragma unroll
    for (int nj = 0; nj < 4; ++nj)
      bfv[nj] = *(const bf16x8*)&Bs[cur][(nj * 16 + fr) * 32 + ksub];
    if (kt + 2 < 72) stage(kt + 2, nxt);
#pragma unroll
    for (int nj = 0; nj < 4; ++nj)
      acc[nj] = __builtin_amdgcn_mfma_f32_16x16x32_bf16(af, bfv[nj], acc[nj], 0, 0, 0);
    cur = (cur == 2) ? 0 : cur + 1;
    nxt = (nxt == 2) ? 0 : nxt + 1;
  }
  const int cc = lane & 15;
  const int rbase = (lane >> 4) * 4;
#pragma unroll
  for (int nj = 0; nj < 4; ++nj) {
    int col = nj * 16 + cc;
    float bb = bias[col];
#pragma unroll
    for (int r = 0; r < 4; ++r) {
      int row = wave * 16 + rbase + r;
      float v = fmaxf(acc[nj][r] + bb, 0.f);
      c1o[(size_t)(b * 4096 + pm + row) * 64 + col] = __float2bfloat16(v);
    }
  }
}

// ---------------------------------------------------------------------------
// ONE prep kernel (ranges as in R12).
// ---------------------------------------------------------------------------
__global__ void prep_all_kernel(
    const float* __restrict__ proj_w, const float* __restrict__ vp_w,
    const float* __restrict__ op_w, const float* __restrict__ l1_w,
    const float* __restrict__ l2_w, const float* __restrict__ so_w,
    const float* __restrict__ aw_w, const float* __restrict__ so_b,
    const float* __restrict__ aw_b, const float* __restrict__ c1_w,
    __hip_bfloat16* __restrict__ proj_wb, __hip_bfloat16* __restrict__ vp_wb,
    __hip_bfloat16* __restrict__ op_wb, __hip_bfloat16* __restrict__ l1_wb,
    __hip_bfloat16* __restrict__ l2_wb, __hip_bfloat16* __restrict__ sowa_wb,
    float* __restrict__ sowa_bias, __hip_bfloat16* __restrict__ wc1b,
    float* __restrict__ zerof) {
  int i = blockIdx.x * 256 + threadIdx.x;
  if (i < 1048576) {
    const float* in;
    __hip_bfloat16* out;
    int j;
    if (i < 65536)       { in = proj_w; out = proj_wb; j = i; }
    else if (i < 163840) { in = vp_w;   out = vp_wb;   j = i - 65536; }
    else if (i < 262144) { in = op_w;   out = op_wb;   j = i - 163840; }
    else if (i < 655360) { in = l1_w;   out = l1_wb;   j = i - 262144; }
    else                 { in = l2_w;   out = l2_wb;   j = i - 655360; }
    float4 v = ((const float4*)in)[j];
    union { ushort4 u; __hip_bfloat16 h[4]; } p;
    p.h[0] = __float2bfloat16(v.x);
    p.h[1] = __float2bfloat16(v.y);
    p.h[2] = __float2bfloat16(v.z);
    p.h[3] = __float2bfloat16(v.w);
    ((ushort4*)out)[j] = p.u;
  } else if (i < 1638400) {
    int j = i - 1048576;
    int il = j / (384 * 256);
    int rem = j - il * 384 * 256;
    int n = rem >> 8, k = rem & 255;
    float v = (n < 256) ? so_w[(size_t)il * 65536 + n * 256 + k]
                        : aw_w[(size_t)il * 32768 + (n - 256) * 256 + k];
    sowa_wb[j] = __float2bfloat16(v);
  } else if (i < 1640704) {
    int j = i - 1638400;
    int il = j / 384, n = j % 384;
    sowa_bias[j] = (n < 256) ? so_b[il * 256 + n] : aw_b[il * 128 + n - 256];
  } else if (i < 1788160) {
    int j = i - 1640704;
    int oc = j / 2304, r = j % 2304;
    int tap = r >> 8, ic = r & 255;
    wc1b[j] = __float2bfloat16(c1_w[(size_t)oc * 2304 + ic * 9 + tap]);
  } else if (i < 1788416) {
    zerof[i - 1788160] = 0.f;
  }
}

// ---------------------------------------------------------------------------
// transpose+convert: f[l][b][c][hw] fp32 -> ft [l][b][hw][c] bf16
// ---------------------------------------------------------------------------
__global__ __launch_bounds__(256) void transpose_f_kernel(
    const float* __restrict__ f0, const float* __restrict__ f1,
    const float* __restrict__ f2, const float* __restrict__ f3,
    __hip_bfloat16* __restrict__ ft) {
  __shared__ float tile[64][65];
  const int HWs[4] = {4096, 1024, 256, 64};
  const int STs[4] = {0, 4096, 5120, 5376};
  int chunk = blockIdx.x, c0 = blockIdx.y * 64, b = blockIdx.z;
  int l, row0;
  get_chunk(chunk, l, row0);
  const float* fin = (l == 0) ? f0 : (l == 1) ? f1 : (l == 2) ? f2 : f3;
  const int HW = HWs[l];
  int t = threadIdx.x;
  int cr = t >> 4, hc4 = (t & 15) * 4;
#pragma unroll
  for (int p = 0; p < 4; ++p) {
    int c = c0 + p * 16 + cr;
    float4 v = *(const float4*)&fin[(size_t)(b * 256 + c) * HW + row0 + hc4];
    tile[p * 16 + cr][hc4 + 0] = v.x;
    tile[p * 16 + cr][hc4 + 1] = v.y;
    tile[p * 16 + cr][hc4 + 2] = v.z;
    tile[p * 16 + cr][hc4 + 3] = v.w;
  }
  __syncthreads();
  size_t obase = (size_t)2 * STs[l] * 256 + ((size_t)b * HW + row0) * 256 + c0;
#pragma unroll
  for (int p = 0; p < 4; ++p) {
    int r = p * 16 + cr;
    union { ushort4 u; __hip_bfloat16 h[4]; } pk;
    pk.h[0] = __float2bfloat16(tile[hc4 + 0][r]);
    pk.h[1] = __float2bfloat16(tile[hc4 + 1][r]);
    pk.h[2] = __float2bfloat16(tile[hc4 + 2][r]);
    pk.h[3] = __float2bfloat16(tile[hc4 + 3][r]);
    *(ushort4*)&ft[obase + (size_t)r * 256 + hc4] = pk.u;
  }
}

// ---------------------------------------------------------------------------
// GroupNorm stats stage 1 (coalesced 64-row chunks, fp32 input).
// ---------------------------------------------------------------------------
__global__ __launch_bounds__(256) void gn_part_kernel(const float* __restrict__ x,
                                                      float2* __restrict__ part) {
  const int STs[4] = {0, 4096, 5120, 5376};
  int chunk = blockIdx.x, b = blockIdx.y;
  int l, row0;
  get_chunk(chunk, l, row0);
  size_t base = ((size_t)b * LQ + STs[l] + row0) * 256;
  int t = threadIdx.x;
  int col4 = t & 63, rb = t >> 6;
  float s = 0.f, ss = 0.f;
#pragma unroll 4
  for (int i = 0; i < 16; ++i) {
    int r = rb + i * 4;
    float4 v = *(const float4*)&x[base + (size_t)r * 256 + col4 * 4];
    s += v.x + v.y + v.z + v.w;
    ss += v.x * v.x + v.y * v.y + v.z * v.z + v.w * v.w;
  }
  __shared__ float sA[256], sB[256];
  sA[t] = s;
  sB[t] = ss;
  __syncthreads();
  if (t < 64) {
    s = sA[t] + sA[t + 64] + sA[t + 128] + sA[t + 192];
    ss = sB[t] + sB[t + 64] + sB[t + 128] + sB[t + 192];
    sA[t] = s;
    sB[t] = ss;
  }
  __syncthreads();
  if (t < 32)
    part[((size_t)b * 85 + chunk) * 32 + t] =
        make_float2(sA[2 * t] + sA[2 * t + 1], sB[2 * t] + sB[2 * t + 1]);
}

// ---------------------------------------------------------------------------
__device__ __forceinline__ void get_level(int t, int& l, int& hw, int& Hl, int& Wl) {
  if (t < 4096)      { l = 0; hw = t;        Hl = 64; Wl = 64; }
  else if (t < 5120) { l = 1; hw = t - 4096; Hl = 32; Wl = 32; }
  else if (t < 5376) { l = 2; hw = t - 5120; Hl = 16; Wl = 16; }
  else               { l = 3; hw = t - 5376; Hl = 8;  Wl = 8;  }
}

// pos embed + reference points + GN finalize (last block). grid = 5441.
__global__ void pos_ref_fin_kernel(const float* __restrict__ level_embed,
                                   float* __restrict__ pos, float* __restrict__ ref,
                                   const float2* __restrict__ part,
                                   float2* __restrict__ stats) {
  if (blockIdx.x == 5440) {
    int t = threadIdx.x;
    int b = t >> 7, rem = t & 127, l = rem >> 5, g = rem & 31;
    const int cnt_[4] = {64, 16, 4, 1};
    const int cb_[4] = {0, 64, 80, 84};
    const int HWs[4] = {4096, 1024, 256, 64};
    float s = 0.f, ss = 0.f;
    for (int i = 0; i < cnt_[l]; ++i) {
      float2 v = part[((size_t)b * 85 + cb_[l] + i) * 32 + g];
      s += v.x;
      ss += v.y;
    }
    float n = (float)(HWs[l] * 8);
    float mu = s / n;
    float var = ss / n - mu * mu;
    stats[(b * 4 + l) * 32 + g] = make_float2(mu, rsqrtf(var + 1e-5f));
    return;
  }
  int idx = blockIdx.x * 256 + threadIdx.x;
  int t = idx >> 8, c = idx & 255;
  int l, hw, Hl, Wl;
  get_level(t, l, hw, Hl, Wl);
  int y = hw / Wl, xx = hw % Wl;
  const float twopi = 6.28318530717958647692f;
  float v; int cc;
  if (c < 128) { v = (float)(y + 1) * twopi / ((float)Hl + 1e-6f); cc = c; }
  else         { v = (float)(xx + 1) * twopi / ((float)Wl + 1e-6f); cc = c - 128; }
  int k = cc >> 1;
  float dim_t = expf((float)k * (logf(10000.0f) / 64.0f));
  float p = v / dim_t;
  float e = (cc & 1) ? cosf(p) : sinf(p);
  pos[idx] = e + level_embed[l * CDIM + c];
  if (c == 0) {
    ref[t * 2]     = ((float)xx + 0.5f) / (float)Wl;
    ref[t * 2 + 1] = ((float)y + 0.5f) / (float)Hl;
  }
}

// GN apply (fp32 in): emits xb + qb = bf16(v + pos); 4 elems/thread
__global__ void gn_apply_kernel(const float* __restrict__ x,
                                __hip_bfloat16* __restrict__ xb,
                                __hip_bfloat16* __restrict__ qb,
                                const float* __restrict__ pos,
                                const float2* __restrict__ stats,
                                const float* __restrict__ gw, const float* __restrict__ gb) {
  int i4 = blockIdx.x * 256 + threadIdx.x;  // 4-elem index
  if (i4 >= BATCH * LQ * 64) return;
  int idx = i4 * 4;
  int c = idx & 255;
  int tok = idx >> 8;
  int b = tok / LQ, t = tok % LQ;
  int l, hw, Hl, Wl;
  get_level(t, l, hw, Hl, Wl);
  float2 st = stats[(b * 4 + l) * 32 + (c >> 3)];
  float4 xv = *(const float4*)&x[idx];
  float4 gwv = *(const float4*)&gw[l * CDIM + c];
  float4 gbv = *(const float4*)&gb[l * CDIM + c];
  float4 pv = *(const float4*)&pos[t * 256 + c];
  float v0 = (xv.x - st.x) * st.y * gwv.x + gbv.x;
  float v1 = (xv.y - st.x) * st.y * gwv.y + gbv.y;
  float v2 = (xv.z - st.x) * st.y * gwv.z + gbv.z;
  float v3 = (xv.w - st.x) * st.y * gwv.w + gbv.w;
  union { ushort4 u; __hip_bfloat16 h[4]; } px, pq;
  px.h[0] = __float2bfloat16(v0);
  px.h[1] = __float2bfloat16(v1);
  px.h[2] = __float2bfloat16(v2);
  px.h[3] = __float2bfloat16(v3);
  pq.h[0] = __float2bfloat16(v0 + pv.x);
  pq.h[1] = __float2bfloat16(v1 + pv.y);
  pq.h[2] = __float2bfloat16(v2 + pv.z);
  pq.h[3] = __float2bfloat16(v3 + pv.w);
  *(ushort4*)&xb[idx] = px.u;
  *(ushort4*)&qb[idx] = pq.u;
}

// ---------------------------------------------------------------------------
// Deformable attention: 4-lane group per (token, head), 8 channels/lane.
// Per level: compute all 4 points' weights/addresses, issue ALL 16 loads,
// then FMA — explicit memory-level parallelism.
// ---------------------------------------------------------------------------
__global__ __launch_bounds__(256) void deform_attn_kernel(
    const __hip_bfloat16* __restrict__ value, const float* __restrict__ comb,
    const float* __restrict__ ref, __hip_bfloat16* __restrict__ out) {
  const int Wl_[4] = {64, 32, 16, 8};
  const int st_[4] = {0, 4096, 5120, 5376};
  int gid = blockIdx.x * 64 + (threadIdx.x >> 2);
  int lane4 = threadIdx.x & 3;
  int h = gid & 7;
  int tok = gid >> 3;
  int b = tok / LQ;
  int qi = tok - b * LQ;

  const float4* awv = (const float4*)(comb + (size_t)tok * 384 + 256 + h * 16);
  float4 q0 = awv[0], q1 = awv[1], q2 = awv[2], q3 = awv[3];
  float logit[16] = {q0.x, q0.y, q0.z, q0.w, q1.x, q1.y, q1.z, q1.w,
                     q2.x, q2.y, q2.z, q2.w, q3.x, q3.y, q3.z, q3.w};
  float mx = -1e30f;
#pragma unroll
  for (int i = 0; i < 16; ++i) mx = fmaxf(mx, logit[i]);
  const float LOG2E = 1.4426950408889634f;
  float ssum = 0.f;
#pragma unroll
  for (int i = 0; i < 16; ++i) {
    logit[i] = exp2f((logit[i] - mx) * LOG2E);
    ssum += logit[i];
  }
  float inv = 1.0f / ssum;

  float rx = ref[qi * 2], ry = ref[qi * 2 + 1];
  const float4* offv = (const float4*)(comb + (size_t)tok * 384 + h * 32);
  float acc[8] = {};

#pragma unroll
  for (int l = 0; l < 4; ++l) {
    const int Wl = Wl_[l];
    const float fW = (float)Wl;
    const __hip_bfloat16* vbase =
        value + ((size_t)b * LQ + st_[l]) * CDIM + h * 32 + lane4 * 8;
    float bx = fmaf(rx, fW, -0.5f);
    float by = fmaf(ry, fW, -0.5f);
    float4 oa = offv[l * 2], ob = offv[l * 2 + 1];
    float oxs[4] = {oa.x, oa.z, ob.x, ob.z};
    float oys[4] = {oa.y, oa.w, ob.y, ob.w};
    // pass 1: weights + addresses + issue all 16 loads
    bf16x8 u[4][4];
    float cw[4][4];
#pragma unroll
    for (int p = 0; p < 4; ++p) {
      float px = bx + oxs[p], py = by + oys[p];
      float wgt = logit[l * 4 + p] * inv;
      float fpx = floorf(px), fpy = floorf(py);
      int x0 = (int)fpx, y0 = (int)fpy;
      float fx = px - fpx, fy = py - fpy;
      float wx0 = (x0 >= 0 && x0 < Wl) ? (1.f - fx) : 0.f;
      float wx1 = (x0 >= -1 && x0 < Wl - 1) ? fx : 0.f;
      float wy0 = (y0 >= 0 && y0 < Wl) ? (wgt * (1.f - fy)) : 0.f;
      float wy1 = (y0 >= -1 && y0 < Wl - 1) ? (wgt * fy) : 0.f;
      int xc0 = min(max(x0, 0), Wl - 1);
      int xc1 = min(max(x0 + 1, 0), Wl - 1);
      int yc0 = min(max(y0, 0), Wl - 1);
      int yc1 = min(max(y0 + 1, 0), Wl - 1);
      const __hip_bfloat16* r0 = vbase + (size_t)(yc0 * Wl) * CDIM;
      const __hip_bfloat16* r1 = vbase + (size_t)(yc1 * Wl) * CDIM;
      u[p][0] = *(const bf16x8*)(r0 + (size_t)xc0 * CDIM);
      u[p][1] = *(const bf16x8*)(r0 + (size_t)xc1 * CDIM);
      u[p][2] = *(const bf16x8*)(r1 + (size_t)xc0 * CDIM);
      u[p][3] = *(const bf16x8*)(r1 + (size_t)xc1 * CDIM);
      cw[p][0] = wy0 * wx0;
      cw[p][1] = wy0 * wx1;
      cw[p][2] = wy1 * wx0;
      cw[p][3] = wy1 * wx1;
    }
    // pass 2: FMAs
#pragma unroll
    for (int p = 0; p < 4; ++p)
#pragma unroll
      for (int cn = 0; cn < 4; ++cn) {
        float w = cw[p][cn];
#pragma unroll
        for (int k = 0; k < 8; ++k)
          acc[k] = fmaf(w, b2f((unsigned short)u[p][cn][k]), acc[k]);
      }
  }
  union { bf16x8 u; __hip_bfloat16 hh[8]; } pk;
#pragma unroll
  for (int k = 0; k < 8; ++k) pk.hh[k] = __float2bfloat16(acc[k]);
  *(bf16x8*)(out + (size_t)tok * CDIM + h * 32 + lane4 * 8) = pk.u;
}

// conv2 NHWC split over taps: part[tap][b][pix][2]
__global__ __launch_bounds__(256) void conv2_part_kernel(
    const __hip_bfloat16* __restrict__ c1o, const float* __restrict__ w,
    float* __restrict__ part) {
  int pix = blockIdx.x * 256 + threadIdx.x;
  int tap = blockIdx.y, b = blockIdx.z;
  int y = pix >> 6, x = pix & 63;
  int dy = tap / 3 - 1, dx = tap % 3 - 1;
  int yy = y + dy, xx = x + dx;
  bool ok = (yy >= 0 && yy < 64 && xx >= 0 && xx < 64);
  float a0 = 0.f, a1 = 0.f;
  if (ok) {
    const __hip_bfloat16* row = c1o + (size_t)(b * 4096 + yy * 64 + xx) * 64;
#pragma unroll
    for (int ic4 = 0; ic4 < 16; ++ic4) {
      ushort4 u = *(const ushort4*)(row + ic4 * 4);
      float f0 = b2f(u.x), f1 = b2f(u.y), f2 = b2f(u.z), f3 = b2f(u.w);
      int ic = ic4 * 4;
      a0 = fmaf(w[(ic + 0) * 9 + tap], f0, a0);
      a0 = fmaf(w[(ic + 1) * 9 + tap], f1, a0);
      a0 = fmaf(w[(ic + 2) * 9 + tap], f2, a0);
      a0 = fmaf(w[(ic + 3) * 9 + tap], f3, a0);
      a1 = fmaf(w[576 + (ic + 0) * 9 + tap], f0, a1);
      a1 = fmaf(w[576 + (ic + 1) * 9 + tap], f1, a1);
      a1 = fmaf(w[576 + (ic + 2) * 9 + tap], f2, a1);
      a1 = fmaf(w[576 + (ic + 3) * 9 + tap], f3, a1);
    }
  }
  float2 o = make_float2(a0, a1);
  *(float2*)&part[((size_t)(tap * BATCH + b) * 4096 + pix) * 2] = o;
}

// tap-sum + bias + 4x bilinear upsample in one pass.
__global__ void upsample2_kernel(const float* __restrict__ part,
                                 const float* __restrict__ bias,
                                 float* __restrict__ out) {
  int idx = blockIdx.x * 256 + threadIdx.x;
  if (idx >= BATCH * 65536) return;
  int X = idx & 255, Y = (idx >> 8) & 255, b = idx >> 16;
  float tx = ((float)X + 0.5f) * 0.25f - 0.5f;
  float ty = ((float)Y + 0.5f) * 0.25f - 0.5f;
  float fxf = floorf(tx), fyf = floorf(ty);
  int x0 = (int)fxf, y0 = (int)fyf;
  float fx = tx - fxf, fy = ty - fyf;
  int x0c = min(max(x0, 0), 63), x1c = min(max(x0 + 1, 0), 63);
  int y0c = min(max(y0, 0), 63), y1c = min(max(y0 + 1, 0), 63);
  int p00 = y0c * 64 + x0c, p01 = y0c * 64 + x1c;
  int p10 = y1c * 64 + x0c, p11 = y1c * 64 + x1c;
  float c00x = 0.f, c00y = 0.f, c01x = 0.f, c01y = 0.f;
  float c10x = 0.f, c10y = 0.f, c11x = 0.f, c11y = 0.f;
#pragma unroll
  for (int tap = 0; tap < 9; ++tap) {
    const float* pp = part + ((size_t)(tap * BATCH + b) * 4096) * 2;
    float2 v00 = *(const float2*)&pp[p00 * 2];
    float2 v01 = *(const float2*)&pp[p01 * 2];
    float2 v10 = *(const float2*)&pp[p10 * 2];
    float2 v11 = *(const float2*)&pp[p11 * 2];
    c00x += v00.x; c00y += v00.y;
    c01x += v01.x; c01y += v01.y;
    c10x += v10.x; c10y += v10.y;
    c11x += v11.x; c11y += v11.y;
  }
  float b0 = bias[0], b1 = bias[1];
  float w00 = (1.f - fy) * (1.f - fx), w01 = (1.f - fy) * fx;
  float w10 = fy * (1.f - fx), w11 = fy * fx;
  float o0 = w00 * (c00x + b0) + w01 * (c01x + b0) + w10 * (c10x + b0) + w11 * (c11x + b0);
  float o1 = w00 * (c00y + b1) + w01 * (c01y + b1) + w10 * (c10y + b1) + w11 * (c11y + b1);
  size_t obase = (size_t)b * 2 * 65536 + (Y << 8) + X;
  out[obase] = o0;
  out[obase + 65536] = o1;
}

// ---------------------------------------------------------------------------
extern "C" void kernel_launch(void* const* d_in, const int* in_sizes, int n_in,
                              void* d_out, int out_size, void* d_ws, size_t ws_size,
                              hipStream_t stream) {
  const float* f[4] = {(const float*)d_in[0], (const float*)d_in[1],
                       (const float*)d_in[2], (const float*)d_in[3]};
  const float* proj_w = (const float*)d_in[4];
  const float* proj_b = (const float*)d_in[5];
  const float* gn_w = (const float*)d_in[6];
  const float* gn_b = (const float*)d_in[7];
  const float* level_embed = (const float*)d_in[8];
  const float* so_w = (const float*)d_in[9];
  const float* so_b = (const float*)d_in[10];
  const float* aw_w = (const float*)d_in[11];
  const float* aw_b = (const float*)d_in[12];
  const float* vp_w = (const float*)d_in[13];
  const float* vp_b = (const float*)d_in[14];
  const float* op_w = (const float*)d_in[15];
  const float* op_b = (const float*)d_in[16];
  const float* n1_w = (const float*)d_in[17];
  const float* n1_b = (const float*)d_in[18];
  const float* l1_w = (const float*)d_in[19];
  const float* l1_b = (const float*)d_in[20];
  const float* l2_w = (const float*)d_in[21];
  const float* l2_b = (const float*)d_in[22];
  const float* n2_w = (const float*)d_in[23];
  const float* n2_b = (const float*)d_in[24];
  const float* c1_w = (const float*)d_in[25];
  const float* c1_b = (const float*)d_in[26];
  const float* c2_w = (const float*)d_in[27];
  const float* c2_b = (const float*)d_in[28];
  (void)in_sizes; (void)n_in; (void)out_size; (void)ws_size;

  float* ws = (float*)d_ws;
  const size_t TOK = (size_t)BATCH * LQ * CDIM;  // 2785280
  size_t o = 0;
  float* x = ws + o;     o += TOK;
  float* comb = ws + o;  o += (size_t)BATCH * LQ * 384;
  float* pos = ws + o;   o += (size_t)LQ * CDIM;
  float* refb = ws + o;  o += 11008;
  float2* stats = (float2*)(ws + o); o += 512;
  float* zerof = ws + o; o += 256;
  float* sowa_bias = ws + o; o += 2304;
  float2* gnpart = (float2*)(ws + o); o += 11008;
  __hip_bfloat16* xb = (__hip_bfloat16*)(ws + o);    o += TOK / 2;
  __hip_bfloat16* qb = (__hip_bfloat16*)(ws + o);    o += TOK / 2;
  __hip_bfloat16* valb = (__hip_bfloat16*)(ws + o);  o += TOK / 2;
  __hip_bfloat16* attnb = (__hip_bfloat16*)(ws + o); o += TOK / 2;
  __hip_bfloat16* ftb = (__hip_bfloat16*)(ws + o);   o += TOK / 2;
  __hip_bfloat16* ff1b = (__hip_bfloat16*)(ws + o);  o += (size_t)BATCH * LQ * FFDIM / 2;
  __hip_bfloat16* sowa_wb = (__hip_bfloat16*)(ws + o); o += 294912;
  __hip_bfloat16* vp_wb = (__hip_bfloat16*)(ws + o); o += 196608;
  __hip_bfloat16* op_wb = (__hip_bfloat16*)(ws + o); o += 196608;
  __hip_bfloat16* l1_wb = (__hip_bfloat16*)(ws + o); o += 786432;
  __hip_bfloat16* l2_wb = (__hip_bfloat16*)(ws + o); o += 786432;
  __hip_bfloat16* proj_wb = (__hip_bfloat16*)(ws + o); o += 131072;
  __hip_bfloat16* wc1b = (__hip_bfloat16*)(ws + o);  o += 73728;
  // head scratch aliases ff1b region (free after encoder)
  __hip_bfloat16* c1ob = ff1b;
  float* part2 = (float*)(ff1b + 524288);

  // 0) all weight prep in one launch
  prep_all_kernel<<<(1788416 + 255) / 256, 256, 0, stream>>>(
      proj_w, vp_w, op_w, l1_w, l2_w, so_w, aw_w, so_b, aw_b, c1_w,
      proj_wb, vp_wb, op_wb, l1_wb, l2_wb, sowa_wb, sowa_bias, wc1b, zerof);

  // 1) input transpose+convert, single-launch input-proj (fp32 out), GN stats
  transpose_f_kernel<<<dim3(85, 4, BATCH), 256, 0, stream>>>(f[0], f[1], f[2], f[3],
                                                             ftb);
  input_proj_kernel<<<170, 256, 0, stream>>>(ftb, proj_wb, proj_b, x);
  gn_part_kernel<<<dim3(85, BATCH), 256, 0, stream>>>(x, gnpart);
  // 2) pos embed + ref + GN finalize (one launch)
  pos_ref_fin_kernel<<<5441, 256, 0, stream>>>(level_embed, pos, refb, gnpart, stats);
  // 3) GN apply -> xb, qb (4 elems/thread)
  gn_apply_kernel<<<(BATCH * LQ * 64 + 255) / 256, 256, 0, stream>>>(
      x, xb, qb, pos, stats, gn_w, gn_b);

  for (int i = 0; i < 6; ++i) {
    const __hip_bfloat16* sowa = sowa_wb + (size_t)i * 98304;
    const __hip_bfloat16* vw = vp_wb + (size_t)i * 65536;
    const __hip_bfloat16* ow = op_wb + (size_t)i * 65536;
    const __hip_bfloat16* w1 = l1_wb + (size_t)i * 262144;
    const __hip_bfloat16* w2 = l2_wb + (size_t)i * 262144;
    const float* vb = vp_b + (size_t)i * CDIM;
    const float* ob = op_b + (size_t)i * CDIM;
    const float* b1 = l1_b + (size_t)i * FFDIM;
    const float* b2 = l2_b + (size_t)i * CDIM;

    gemm_dual_kernel<<<850, 256, 0, stream>>>(xb, vw, vb, valb, qb, sowa,
                                              sowa_bias + i * 384, comb);
    deform_attn_kernel<<<BATCH * LQ * 8 / 64, 256, 0, stream>>>(valb, comb, refb,
                                                                attnb);
    gemm_ln_kernel<false><<<340, 256, 0, stream>>>(
        attnb, ow, ob, xb, nullptr, nullptr,
        n1_w + (size_t)i * CDIM, n1_b + (size_t)i * CDIM, CDIM);
    ffn1_kernel<<<1360, 256, 0, stream>>>(xb, w1, b1, ff1b);
    gemm_ln_kernel<true><<<340, 256, 0, stream>>>(
        ff1b, w2, b2, xb, qb, pos,
        n2_w + (size_t)i * CDIM, n2_b + (size_t)i * CDIM, FFDIM);
  }

  // head
  conv1_mfma_kernel<<<128, 256, 0, stream>>>(xb, wc1b, c1_b,
                                             (const __hip_bfloat16*)zerof, c1ob);
  conv2_part_kernel<<<dim3(16, 9, BATCH), 256, 0, stream>>>(c1ob, c2_w, part2);
  upsample2_kernel<<<(BATCH * 65536 + 255) / 256, 256, 0, stream>>>(part2, c2_b,
                                                                    (float*)d_out);
}